// Round 10
// baseline (107.188 us; speedup 1.0000x reference)
//
#include <hip/hip_runtime.h>
#include <hip/hip_fp16.h>
#include <cstdint>
#include <cstddef>

#define BATCH 8
#define NPTS  2048
#define CH1   64
#define CH2   128
#define NSAMP 64

typedef _Float16 half8v  __attribute__((ext_vector_type(8)));
typedef _Float16 half2v  __attribute__((ext_vector_type(2)));
typedef float    float4v __attribute__((ext_vector_type(4)));
typedef unsigned uint4v  __attribute__((ext_vector_type(4)));

// packed f16 max, compiler-visible (lowers to v_pk_max_f16)
__device__ inline unsigned pmax(unsigned a, unsigned b) {
  half2v ha = __builtin_bit_cast(half2v, a);
  half2v hb = __builtin_bit_cast(half2v, b);
  return __builtin_bit_cast(unsigned, __builtin_elementwise_max(ha, hb));
}

__device__ inline uint4v pk4max(uint4v a, uint4v b) {
  uint4v d;
#pragma unroll
  for (int i = 0; i < 4; ++i) d[i] = pmax(a[i], b[i]);
  return d;
}

__device__ inline float h2lo(unsigned u) {
  return (float)__builtin_bit_cast(half2v, u)[0];
}
__device__ inline float h2hi(unsigned u) {
  return (float)__builtin_bit_cast(half2v, u)[1];
}

// ---------------------------------------------------------------------------
// Kernel 1: per-point MLP via MFMA (128 x 16384 x 64 fp16 GEMM). Unchanged
// from R7 (measured fast). Also emits xyzq[pt] = {x,y,z,|p|^2}.
// ---------------------------------------------------------------------------
__global__ __launch_bounds__(256) void mlp_kernel(
    const float* __restrict__ x,
    const float* __restrict__ W1, const float* __restrict__ b1,
    const float* __restrict__ W2, const float* __restrict__ b2,
    __half* __restrict__ h2, float4v* __restrict__ xyzq) {
  const int t = threadIdx.x;
  const int wave = t >> 6;
  const int lane = t & 63;
  const int n = lane & 15;
  const int quad = lane >> 4;
  const int pti = wave >> 1;
  const int mh  = wave & 1;
  const int base = blockIdx.x * 32;

  if (t < 32) {
    const int pt = base + t;
    const float X = x[pt * 3 + 0];
    const float Y = x[pt * 3 + 1];
    const float Z = x[pt * 3 + 2];
    float4v v;
    v[0] = X; v[1] = Y; v[2] = Z; v[3] = fmaf(Z, Z, fmaf(Y, Y, X * X));
    xyzq[pt] = v;
  }

  float w1x[16], w1y[16], w1z[16], b1v[16];
#pragma unroll
  for (int j = 0; j < 16; ++j) {
    const int o = quad * 8 + (j & 7) + ((j < 8) ? 0 : 32);
    w1x[j] = W1[o * 3 + 0];
    w1y[j] = W1[o * 3 + 1];
    w1z[j] = W1[o * 3 + 2];
    b1v[j] = b1[o];
  }

  half8v afrag[4][2];
  float4v bias[4];
#pragma unroll
  for (int mt = 0; mt < 4; ++mt) {
    const int mtg = mh * 4 + mt;
    const int m = mtg * 16 + n;
#pragma unroll
    for (int kf = 0; kf < 2; ++kf) {
      const float4v* wp = (const float4v*)(W2 + m * CH1 + kf * 32 + quad * 8);
      const float4v lo = wp[0];
      const float4v hi = wp[1];
#pragma unroll
      for (int e = 0; e < 4; ++e) {
        afrag[mt][kf][e]     = (_Float16)lo[e];
        afrag[mt][kf][4 + e] = (_Float16)hi[e];
      }
    }
    bias[mt] = *(const float4v*)(b2 + mtg * 16 + quad * 4);
  }

  const int pt = base + pti * 16 + n;
  const float X = x[pt * 3 + 0];
  const float Y = x[pt * 3 + 1];
  const float Z = x[pt * 3 + 2];
  half8v bf0, bf1;
#pragma unroll
  for (int j = 0; j < 8; ++j) {
    const float ha = fmaxf(fmaf(w1z[j], Z, fmaf(w1y[j], Y, fmaf(w1x[j], X, b1v[j]))), 0.f);
    const float hb = fmaxf(fmaf(w1z[8 + j], Z, fmaf(w1y[8 + j], Y, fmaf(w1x[8 + j], X, b1v[8 + j]))), 0.f);
    bf0[j] = (_Float16)ha;
    bf1[j] = (_Float16)hb;
  }

  __half* hrow = h2 + (size_t)pt * CH2;
#pragma unroll
  for (int mt = 0; mt < 4; ++mt) {
    const int mtg = mh * 4 + mt;
    float4v acc = bias[mt];
    acc = __builtin_amdgcn_mfma_f32_16x16x32_f16(afrag[mt][0], bf0, acc, 0, 0, 0);
    acc = __builtin_amdgcn_mfma_f32_16x16x32_f16(afrag[mt][1], bf1, acc, 0, 0, 0);
    const int p0 = mtg * 16 + quad * 4;
    half2v lo2, hi2;
    lo2[0] = (_Float16)fmaxf(acc[0], 0.f);
    lo2[1] = (_Float16)fmaxf(acc[1], 0.f);
    hi2[0] = (_Float16)fmaxf(acc[2], 0.f);
    hi2[1] = (_Float16)fmaxf(acc[3], 0.f);
    uint2 pk;
    pk.x = __builtin_bit_cast(unsigned, lo2);
    pk.y = __builtin_bit_cast(unsigned, hi2);
    *(uint2*)(hrow + p0) = pk;
  }
}

// ---------------------------------------------------------------------------
// Kernel 2: ball query + max-pool. One wave per query, 4 queries/block.
// Phase 2's 16 gather loads are ONE asm volatile block using the flat
// 64-bit vaddr form (addresses precomputed as uint64 VGPR pairs): 16
// back-to-back global_load_dwordx4 + a single s_waitcnt vmcnt(0). R4-R8
// proved the compiler always re-serializes these loads (VGPR stuck at 32,
// 8 serial L2 round-trips); inside one asm block it cannot.
// ---------------------------------------------------------------------------
__global__ __launch_bounds__(256, 4) void query_kernel(
    const float4v* __restrict__ xyzq,
    const __half* __restrict__ h2,
    float* __restrict__ out) {
  __shared__ int list[4][NSAMP];
  __shared__ unsigned res[4][64];

  const int t = threadIdx.x;
  const int wave = t >> 6;
  const int lane = t & 63;
  const int s0 = blockIdx.x * 4;
  const int q = s0 + wave;
  const int b = q >> 11;
  const int s = q & (NPTS - 1);

  const float4v* xq = xyzq + (size_t)b * NPTS;
  const float4v qv = xq[s];
  const float qx = qv[0], qy = qv[1], qz = qv[2], dqf = qv[3];
  const double dq = (double)qx * qx + (double)qy * qy + (double)qz * qz;
  const unsigned long long lt = (1ull << lane) - 1ull;

  // ---- Phase 1: first NSAMP in-radius hits, ascending index ----
  int count = 0;
  for (int g = 0; g < NPTS / 256 && count < NSAMP; ++g) {
    float4v pv[4];
#pragma unroll
    for (int j = 0; j < 4; ++j) pv[j] = xq[g * 256 + j * 64 + lane];
#pragma unroll
    for (int j = 0; j < 4; ++j) {
      const int m = g * 256 + j * 64 + lane;
      const float px = pv[j][0], py = pv[j][1], pz = pv[j][2];
      const float dot = fmaf(qz, pz, fmaf(qy, py, qx * px));
      const float dist = fmaf(-2.f, dot, dqf + pv[j][3]);
      bool hit;
      if (__ballot(__builtin_fabsf(dist - 0.36f) <= 3e-5f)) {
        const double dm = (double)px * px + (double)py * py + (double)pz * pz;
        const double dd = (double)qx * px + (double)qy * py + (double)qz * pz;
        hit = !((dq + dm - 2.0 * dd) > 0.36);
      } else {
        hit = !(dist > 0.36f);
      }
      const unsigned long long mask = __ballot(hit);
      if (hit) {
        const int pos = count + __popcll(mask & lt);
        if (pos < NSAMP) list[wave][pos] = m;
      }
      count += __popcll(mask);
    }
  }
  if (count > NSAMP) count = NSAMP;
  const int first = list[wave][0];      // self is always a hit
  if (lane >= count) list[wave][lane] = first;

  // ---- Phase 2: 8 hit-slots x 16 channels per lane ----
  const int h = lane & 7;
  const int c = lane >> 3;
  const unsigned long long hbase =
      (unsigned long long)(h2 + (size_t)b * NPTS * CH2) + (unsigned)(c * 32);

  unsigned long long ad[8];
#pragma unroll
  for (int r = 0; r < 8; ++r) {
    const int m = list[wave][r * 8 + h];
    ad[r] = hbase + (unsigned)(m * 256);
  }

  uint4v la[8], lb[8];
  asm volatile(
      "global_load_dwordx4 %0, %16, off\n\t"
      "global_load_dwordx4 %1, %16, off offset:16\n\t"
      "global_load_dwordx4 %2, %17, off\n\t"
      "global_load_dwordx4 %3, %17, off offset:16\n\t"
      "global_load_dwordx4 %4, %18, off\n\t"
      "global_load_dwordx4 %5, %18, off offset:16\n\t"
      "global_load_dwordx4 %6, %19, off\n\t"
      "global_load_dwordx4 %7, %19, off offset:16\n\t"
      "global_load_dwordx4 %8, %20, off\n\t"
      "global_load_dwordx4 %9, %20, off offset:16\n\t"
      "global_load_dwordx4 %10, %21, off\n\t"
      "global_load_dwordx4 %11, %21, off offset:16\n\t"
      "global_load_dwordx4 %12, %22, off\n\t"
      "global_load_dwordx4 %13, %22, off offset:16\n\t"
      "global_load_dwordx4 %14, %23, off\n\t"
      "global_load_dwordx4 %15, %23, off offset:16\n\t"
      "s_waitcnt vmcnt(0)"
      : "=&v"(la[0]), "=&v"(lb[0]), "=&v"(la[1]), "=&v"(lb[1]),
        "=&v"(la[2]), "=&v"(lb[2]), "=&v"(la[3]), "=&v"(lb[3]),
        "=&v"(la[4]), "=&v"(lb[4]), "=&v"(la[5]), "=&v"(lb[5]),
        "=&v"(la[6]), "=&v"(lb[6]), "=&v"(la[7]), "=&v"(lb[7])
      : "v"(ad[0]), "v"(ad[1]), "v"(ad[2]), "v"(ad[3]),
        "v"(ad[4]), "v"(ad[5]), "v"(ad[6]), "v"(ad[7])
      : "memory");

  // pairwise max tree over the 8 hit rows
  uint4v A = pk4max(pk4max(pk4max(la[0], la[1]), pk4max(la[2], la[3])),
                    pk4max(pk4max(la[4], la[5]), pk4max(la[6], la[7])));
  uint4v B = pk4max(pk4max(pk4max(lb[0], lb[1]), pk4max(lb[2], lb[3])),
                    pk4max(pk4max(lb[4], lb[5]), pk4max(lb[6], lb[7])));

  unsigned a0 = A[0], a1 = A[1], a2 = A[2], a3 = A[3];
  unsigned a4 = B[0], a5 = B[1], a6 = B[2], a7 = B[3];

  // xor-butterfly over hit-slot bits (lane bits 0..2)
#define RED_STEP(IMM)                                                         \
  a0 = pmax(a0, (unsigned)__builtin_amdgcn_ds_swizzle((int)a0, IMM));         \
  a1 = pmax(a1, (unsigned)__builtin_amdgcn_ds_swizzle((int)a1, IMM));         \
  a2 = pmax(a2, (unsigned)__builtin_amdgcn_ds_swizzle((int)a2, IMM));         \
  a3 = pmax(a3, (unsigned)__builtin_amdgcn_ds_swizzle((int)a3, IMM));         \
  a4 = pmax(a4, (unsigned)__builtin_amdgcn_ds_swizzle((int)a4, IMM));         \
  a5 = pmax(a5, (unsigned)__builtin_amdgcn_ds_swizzle((int)a5, IMM));         \
  a6 = pmax(a6, (unsigned)__builtin_amdgcn_ds_swizzle((int)a6, IMM));         \
  a7 = pmax(a7, (unsigned)__builtin_amdgcn_ds_swizzle((int)a7, IMM));
  RED_STEP(0x041F)   // xor 1
  RED_STEP(0x081F)   // xor 2
  RED_STEP(0x101F)   // xor 4
#undef RED_STEP

  const unsigned s1 = (h & 1) ? a1 : a0;
  const unsigned s2 = (h & 1) ? a3 : a2;
  const unsigned s3 = (h & 1) ? a5 : a4;
  const unsigned s4 = (h & 1) ? a7 : a6;
  const unsigned t1 = (h & 2) ? s2 : s1;
  const unsigned t2 = (h & 2) ? s4 : s3;
  const unsigned vsel = (h & 4) ? t2 : t1;
  res[wave][lane] = vsel;

  __syncthreads();

  // ---- Writeout: coalesced 16-B segments across the block's 4 queries ----
  {
    const int p = t >> 1;
    const int ss = (t & 1) * 2;
    const unsigned r0 = res[ss][p >> 1];
    const unsigned r1 = res[ss + 1][p >> 1];
    float2 w;
    w.x = (p & 1) ? h2hi(r0) : h2lo(r0);
    w.y = (p & 1) ? h2hi(r1) : h2lo(r1);
    const size_t ob = (size_t)b * CH2 * NPTS;
    *(float2*)(out + ob + (size_t)p * NPTS + (s0 & (NPTS - 1)) + ss) = w;
  }
}

// ---------------------------------------------------------------------------
extern "C" void kernel_launch(void* const* d_in, const int* in_sizes, int n_in,
                              void* d_out, int out_size, void* d_ws, size_t ws_size,
                              hipStream_t stream) {
  const float* x  = (const float*)d_in[0];
  const float* W1 = (const float*)d_in[1];
  const float* b1 = (const float*)d_in[2];
  const float* W2 = (const float*)d_in[3];
  const float* b2 = (const float*)d_in[4];
  float* out = (float*)d_out;

  __half*  h2   = (__half*)d_ws;                                     // 4 MB
  float4v* xyzq = (float4v*)((char*)d_ws + (size_t)4 * 1024 * 1024); // 256 KB

  mlp_kernel<<<(BATCH * NPTS) / 32, 256, 0, stream>>>(
      x, W1, b1, W2, b2, h2, xyzq);
  query_kernel<<<(BATCH * NPTS) / 4, 256, 0, stream>>>(xyzq, h2, out);
}

// Round 11
// 92.670 us; speedup vs baseline: 1.1567x; 1.1567x over previous
//
#include <hip/hip_runtime.h>
#include <hip/hip_fp16.h>
#include <cstdint>
#include <cstddef>

#define BATCH 8
#define NPTS  2048
#define CH1   64
#define CH2   128
#define NSAMP 64

typedef _Float16 half8v  __attribute__((ext_vector_type(8)));
typedef _Float16 half2v  __attribute__((ext_vector_type(2)));
typedef float    float4v __attribute__((ext_vector_type(4)));
typedef unsigned uint4v  __attribute__((ext_vector_type(4)));

// packed f16 max, compiler-visible (lowers to v_pk_max_f16)
__device__ inline unsigned pmax(unsigned a, unsigned b) {
  half2v ha = __builtin_bit_cast(half2v, a);
  half2v hb = __builtin_bit_cast(half2v, b);
  return __builtin_bit_cast(unsigned, __builtin_elementwise_max(ha, hb));
}

__device__ inline uint4v pk4max(uint4v a, uint4v b) {
  uint4v d;
#pragma unroll
  for (int i = 0; i < 4; ++i) d[i] = pmax(a[i], b[i]);
  return d;
}

__device__ inline float h2lo(unsigned u) {
  return (float)__builtin_bit_cast(half2v, u)[0];
}
__device__ inline float h2hi(unsigned u) {
  return (float)__builtin_bit_cast(half2v, u)[1];
}

// ---------------------------------------------------------------------------
// Kernel 1: per-point MLP via MFMA (128 x 16384 x 64 fp16 GEMM). Unchanged
// from R7/R10 (measured fast). Also emits xyzq[pt] = {x,y,z,|p|^2}.
// ---------------------------------------------------------------------------
__global__ __launch_bounds__(256) void mlp_kernel(
    const float* __restrict__ x,
    const float* __restrict__ W1, const float* __restrict__ b1,
    const float* __restrict__ W2, const float* __restrict__ b2,
    __half* __restrict__ h2, float4v* __restrict__ xyzq) {
  const int t = threadIdx.x;
  const int wave = t >> 6;
  const int lane = t & 63;
  const int n = lane & 15;
  const int quad = lane >> 4;
  const int pti = wave >> 1;
  const int mh  = wave & 1;
  const int base = blockIdx.x * 32;

  if (t < 32) {
    const int pt = base + t;
    const float X = x[pt * 3 + 0];
    const float Y = x[pt * 3 + 1];
    const float Z = x[pt * 3 + 2];
    float4v v;
    v[0] = X; v[1] = Y; v[2] = Z; v[3] = fmaf(Z, Z, fmaf(Y, Y, X * X));
    xyzq[pt] = v;
  }

  float w1x[16], w1y[16], w1z[16], b1v[16];
#pragma unroll
  for (int j = 0; j < 16; ++j) {
    const int o = quad * 8 + (j & 7) + ((j < 8) ? 0 : 32);
    w1x[j] = W1[o * 3 + 0];
    w1y[j] = W1[o * 3 + 1];
    w1z[j] = W1[o * 3 + 2];
    b1v[j] = b1[o];
  }

  half8v afrag[4][2];
  float4v bias[4];
#pragma unroll
  for (int mt = 0; mt < 4; ++mt) {
    const int mtg = mh * 4 + mt;
    const int m = mtg * 16 + n;
#pragma unroll
    for (int kf = 0; kf < 2; ++kf) {
      const float4v* wp = (const float4v*)(W2 + m * CH1 + kf * 32 + quad * 8);
      const float4v lo = wp[0];
      const float4v hi = wp[1];
#pragma unroll
      for (int e = 0; e < 4; ++e) {
        afrag[mt][kf][e]     = (_Float16)lo[e];
        afrag[mt][kf][4 + e] = (_Float16)hi[e];
      }
    }
    bias[mt] = *(const float4v*)(b2 + mtg * 16 + quad * 4);
  }

  const int pt = base + pti * 16 + n;
  const float X = x[pt * 3 + 0];
  const float Y = x[pt * 3 + 1];
  const float Z = x[pt * 3 + 2];
  half8v bf0, bf1;
#pragma unroll
  for (int j = 0; j < 8; ++j) {
    const float ha = fmaxf(fmaf(w1z[j], Z, fmaf(w1y[j], Y, fmaf(w1x[j], X, b1v[j]))), 0.f);
    const float hb = fmaxf(fmaf(w1z[8 + j], Z, fmaf(w1y[8 + j], Y, fmaf(w1x[8 + j], X, b1v[8 + j]))), 0.f);
    bf0[j] = (_Float16)ha;
    bf1[j] = (_Float16)hb;
  }

  __half* hrow = h2 + (size_t)pt * CH2;
#pragma unroll
  for (int mt = 0; mt < 4; ++mt) {
    const int mtg = mh * 4 + mt;
    float4v acc = bias[mt];
    acc = __builtin_amdgcn_mfma_f32_16x16x32_f16(afrag[mt][0], bf0, acc, 0, 0, 0);
    acc = __builtin_amdgcn_mfma_f32_16x16x32_f16(afrag[mt][1], bf1, acc, 0, 0, 0);
    const int p0 = mtg * 16 + quad * 4;
    half2v lo2, hi2;
    lo2[0] = (_Float16)fmaxf(acc[0], 0.f);
    lo2[1] = (_Float16)fmaxf(acc[1], 0.f);
    hi2[0] = (_Float16)fmaxf(acc[2], 0.f);
    hi2[1] = (_Float16)fmaxf(acc[3], 0.f);
    uint2 pk;
    pk.x = __builtin_bit_cast(unsigned, lo2);
    pk.y = __builtin_bit_cast(unsigned, hi2);
    *(uint2*)(hrow + p0) = pk;
  }
}

// ---------------------------------------------------------------------------
// Kernel 2: ONE BLOCK (4 waves) PER QUERY. R1-R10's one-wave-per-query
// designs all plateaued at ~41 us regardless of phase-2 structure -> the
// bottleneck is the per-query serial critical path. Here the block's 4
// waves scan 256 candidates at once (cross-wave prefix via LDS), and the
// feature gather is fully coalesced: thread t loads 16 B of row
// list[r*16 + t>>4] (4 contiguous 256-B rows per wave-instruction), 4
// rounds, asm-bursted. Row reduction via 4-KB LDS staging.
// ---------------------------------------------------------------------------
__global__ __launch_bounds__(256) void query_kernel(
    const float4v* __restrict__ xyzq,
    const __half* __restrict__ h2,
    float* __restrict__ out) {
  __shared__ int list[NSAMP];
  __shared__ unsigned cnt[4];
  __shared__ uint4v partial[256];   // 4 KB

  const int t = threadIdx.x;
  const int wave = t >> 6;
  const int lane = t & 63;
  const int q = blockIdx.x;
  const int b = q >> 11;
  const int s = q & (NPTS - 1);

  const float4v* xq = xyzq + (size_t)b * NPTS;
  const float4v qv = xq[s];
  const float qx = qv[0], qy = qv[1], qz = qv[2], dqf = qv[3];
  const double dq = (double)qx * qx + (double)qy * qy + (double)qz * qz;
  const unsigned long long lt = (1ull << lane) - 1ull;

  // ---- Phase 1: first NSAMP in-radius hits (ascending index), 256/iter ----
  int count = 0;
  for (int base = 0; base < NPTS && count < NSAMP; base += 256) {
    const int m = base + wave * 64 + lane;
    const float4v pv = xq[m];
    const float px = pv[0], py = pv[1], pz = pv[2];
    const float dot = fmaf(qz, pz, fmaf(qy, py, qx * px));
    const float dist = fmaf(-2.f, dot, dqf + pv[3]);
    bool hit;
    if (__ballot(__builtin_fabsf(dist - 0.36f) <= 3e-5f)) {
      // rare exact path: fp64, same evaluation as the np reference
      const double dm = (double)px * px + (double)py * py + (double)pz * pz;
      const double dd = (double)qx * px + (double)qy * py + (double)qz * pz;
      hit = !((dq + dm - 2.0 * dd) > 0.36);
    } else {
      hit = !(dist > 0.36f);
    }
    const unsigned long long mask = __ballot(hit);
    if (lane == 0) cnt[wave] = (unsigned)__popcll(mask);
    __syncthreads();
    int pre = count;
#pragma unroll
    for (int w = 0; w < 3; ++w)
      if (wave > w) pre += (int)cnt[w];
    if (hit) {
      const int pos = pre + __popcll(mask & lt);
      if (pos < NSAMP) list[pos] = m;
    }
    count += (int)(cnt[0] + cnt[1] + cnt[2] + cnt[3]);
    __syncthreads();   // protect cnt (and list) before next iteration
  }
  if (count > NSAMP) count = NSAMP;
  if (t >= count && t < NSAMP) list[t] = list[0];  // self guarantees count>=1
  __syncthreads();

  // ---- Phase 2: coalesced gather. thread t -> rows r*16 + (t>>4),
  //      16-B channel slice (t&15). 4 rounds, one asm burst. ----
  const int rowsel = t >> 4;   // 0..15
  const int csl = t & 15;      // 0..15 (16 B = 8 channels)
  const unsigned long long hb =
      (unsigned long long)(h2 + (size_t)b * NPTS * CH2) + (unsigned)(csl * 16);

  unsigned long long ad[4];
#pragma unroll
  for (int r = 0; r < 4; ++r)
    ad[r] = hb + (unsigned)(list[r * 16 + rowsel] * 256);

  uint4v v0, v1, v2, v3;
  asm volatile(
      "global_load_dwordx4 %0, %4, off\n\t"
      "global_load_dwordx4 %1, %5, off\n\t"
      "global_load_dwordx4 %2, %6, off\n\t"
      "global_load_dwordx4 %3, %7, off\n\t"
      "s_waitcnt vmcnt(0)"
      : "=&v"(v0), "=&v"(v1), "=&v"(v2), "=&v"(v3)
      : "v"(ad[0]), "v"(ad[1]), "v"(ad[2]), "v"(ad[3])
      : "memory");

  partial[t] = pk4max(pk4max(v0, v1), pk4max(v2, v3));
  __syncthreads();

  // ---- Final reduction: 64 threads, one dword (2 channels) each ----
  if (t < 64) {
    const int cs = t >> 2;      // which 16-B slice (0..15)
    const int d  = t & 3;       // dword within slice
    const unsigned* pl = (const unsigned*)&partial[0];
    unsigned m = 0;
#pragma unroll
    for (int rs = 0; rs < 16; ++rs)
      m = pmax(m, pl[(rs * 16 + cs) * 4 + d]);
    const size_t ob = (size_t)b * CH2 * NPTS;
    out[ob + (size_t)(2 * t) * NPTS + s]     = h2lo(m);
    out[ob + (size_t)(2 * t + 1) * NPTS + s] = h2hi(m);
  }
}

// ---------------------------------------------------------------------------
extern "C" void kernel_launch(void* const* d_in, const int* in_sizes, int n_in,
                              void* d_out, int out_size, void* d_ws, size_t ws_size,
                              hipStream_t stream) {
  const float* x  = (const float*)d_in[0];
  const float* W1 = (const float*)d_in[1];
  const float* b1 = (const float*)d_in[2];
  const float* W2 = (const float*)d_in[3];
  const float* b2 = (const float*)d_in[4];
  float* out = (float*)d_out;

  __half*  h2   = (__half*)d_ws;                                     // 4 MB
  float4v* xyzq = (float4v*)((char*)d_ws + (size_t)4 * 1024 * 1024); // 256 KB

  mlp_kernel<<<(BATCH * NPTS) / 32, 256, 0, stream>>>(
      x, W1, b1, W2, b2, h2, xyzq);
  query_kernel<<<BATCH * NPTS, 256, 0, stream>>>(xyzq, h2, out);
}

// Round 12
// 88.177 us; speedup vs baseline: 1.2156x; 1.0510x over previous
//
#include <hip/hip_runtime.h>
#include <hip/hip_fp16.h>
#include <cstdint>
#include <cstddef>

#define BATCH 8
#define NPTS  2048
#define CH1   64
#define CH2   128
#define NSAMP 64

typedef _Float16 half8v  __attribute__((ext_vector_type(8)));
typedef _Float16 half2v  __attribute__((ext_vector_type(2)));
typedef float    float4v __attribute__((ext_vector_type(4)));
typedef unsigned uint4v  __attribute__((ext_vector_type(4)));

// packed f16 max, compiler-visible (lowers to v_pk_max_f16)
__device__ inline unsigned pmax(unsigned a, unsigned b) {
  half2v ha = __builtin_bit_cast(half2v, a);
  half2v hb = __builtin_bit_cast(half2v, b);
  return __builtin_bit_cast(unsigned, __builtin_elementwise_max(ha, hb));
}

__device__ inline uint4v pk4max(uint4v a, uint4v b) {
  uint4v d;
#pragma unroll
  for (int i = 0; i < 4; ++i) d[i] = pmax(a[i], b[i]);
  return d;
}

__device__ inline float h2lo(unsigned u) {
  return (float)__builtin_bit_cast(half2v, u)[0];
}
__device__ inline float h2hi(unsigned u) {
  return (float)__builtin_bit_cast(half2v, u)[1];
}

// ---------------------------------------------------------------------------
// Kernel 1: per-point MLP via MFMA (128 x 16384 x 64 fp16 GEMM). Unchanged
// from R7/R10 (measured fast). Also emits xyzq[pt] = {x,y,z,|p|^2}.
// ---------------------------------------------------------------------------
__global__ __launch_bounds__(256) void mlp_kernel(
    const float* __restrict__ x,
    const float* __restrict__ W1, const float* __restrict__ b1,
    const float* __restrict__ W2, const float* __restrict__ b2,
    __half* __restrict__ h2, float4v* __restrict__ xyzq) {
  const int t = threadIdx.x;
  const int wave = t >> 6;
  const int lane = t & 63;
  const int n = lane & 15;
  const int quad = lane >> 4;
  const int pti = wave >> 1;
  const int mh  = wave & 1;
  const int base = blockIdx.x * 32;

  if (t < 32) {
    const int pt = base + t;
    const float X = x[pt * 3 + 0];
    const float Y = x[pt * 3 + 1];
    const float Z = x[pt * 3 + 2];
    float4v v;
    v[0] = X; v[1] = Y; v[2] = Z; v[3] = fmaf(Z, Z, fmaf(Y, Y, X * X));
    xyzq[pt] = v;
  }

  float w1x[16], w1y[16], w1z[16], b1v[16];
#pragma unroll
  for (int j = 0; j < 16; ++j) {
    const int o = quad * 8 + (j & 7) + ((j < 8) ? 0 : 32);
    w1x[j] = W1[o * 3 + 0];
    w1y[j] = W1[o * 3 + 1];
    w1z[j] = W1[o * 3 + 2];
    b1v[j] = b1[o];
  }

  half8v afrag[4][2];
  float4v bias[4];
#pragma unroll
  for (int mt = 0; mt < 4; ++mt) {
    const int mtg = mh * 4 + mt;
    const int m = mtg * 16 + n;
#pragma unroll
    for (int kf = 0; kf < 2; ++kf) {
      const float4v* wp = (const float4v*)(W2 + m * CH1 + kf * 32 + quad * 8);
      const float4v lo = wp[0];
      const float4v hi = wp[1];
#pragma unroll
      for (int e = 0; e < 4; ++e) {
        afrag[mt][kf][e]     = (_Float16)lo[e];
        afrag[mt][kf][4 + e] = (_Float16)hi[e];
      }
    }
    bias[mt] = *(const float4v*)(b2 + mtg * 16 + quad * 4);
  }

  const int pt = base + pti * 16 + n;
  const float X = x[pt * 3 + 0];
  const float Y = x[pt * 3 + 1];
  const float Z = x[pt * 3 + 2];
  half8v bf0, bf1;
#pragma unroll
  for (int j = 0; j < 8; ++j) {
    const float ha = fmaxf(fmaf(w1z[j], Z, fmaf(w1y[j], Y, fmaf(w1x[j], X, b1v[j]))), 0.f);
    const float hb = fmaxf(fmaf(w1z[8 + j], Z, fmaf(w1y[8 + j], Y, fmaf(w1x[8 + j], X, b1v[8 + j]))), 0.f);
    bf0[j] = (_Float16)ha;
    bf1[j] = (_Float16)hb;
  }

  __half* hrow = h2 + (size_t)pt * CH2;
#pragma unroll
  for (int mt = 0; mt < 4; ++mt) {
    const int mtg = mh * 4 + mt;
    float4v acc = bias[mt];
    acc = __builtin_amdgcn_mfma_f32_16x16x32_f16(afrag[mt][0], bf0, acc, 0, 0, 0);
    acc = __builtin_amdgcn_mfma_f32_16x16x32_f16(afrag[mt][1], bf1, acc, 0, 0, 0);
    const int p0 = mtg * 16 + quad * 4;
    half2v lo2, hi2;
    lo2[0] = (_Float16)fmaxf(acc[0], 0.f);
    lo2[1] = (_Float16)fmaxf(acc[1], 0.f);
    hi2[0] = (_Float16)fmaxf(acc[2], 0.f);
    hi2[1] = (_Float16)fmaxf(acc[3], 0.f);
    uint2 pk;
    pk.x = __builtin_bit_cast(unsigned, lo2);
    pk.y = __builtin_bit_cast(unsigned, hi2);
    *(uint2*)(hrow + p0) = pk;
  }
}

// ---------------------------------------------------------------------------
// Kernel 2: one block (4 waves) per query (R11 structure, 107->92.7 us).
// R12 adds:
//  - XCD swizzle q = (bid&7)<<11 | bid>>3: XCD x owns batch b=x entirely ->
//    xyzq (32 KB) becomes L1-resident, h2 (512 KB) L2-resident, and each
//    128-B output line is written by blocks of ONE XCD (kills the 2x HBM
//    write amplification measured through R10).
//  - single __syncthreads per phase-1 iteration (parity-double-buffered cnt).
// ---------------------------------------------------------------------------
__global__ __launch_bounds__(256) void query_kernel(
    const float4v* __restrict__ xyzq,
    const __half* __restrict__ h2,
    float* __restrict__ out) {
  __shared__ int list[NSAMP];
  __shared__ unsigned cnt[2][4];
  __shared__ uint4v partial[256];   // 4 KB

  const int t = threadIdx.x;
  const int wave = t >> 6;
  const int lane = t & 63;
  const int bid = blockIdx.x;
  const int q = ((bid & 7) << 11) | (bid >> 3);   // XCD-aware swizzle
  const int b = q >> 11;                          // == bid & 7 == XCD id
  const int s = q & (NPTS - 1);

  const float4v* xq = xyzq + (size_t)b * NPTS;
  const float4v qv = xq[s];
  const float qx = qv[0], qy = qv[1], qz = qv[2], dqf = qv[3];
  const double dq = (double)qx * qx + (double)qy * qy + (double)qz * qz;
  const unsigned long long lt = (1ull << lane) - 1ull;

  // ---- Phase 1: first NSAMP in-radius hits (ascending index), 256/iter ----
  int count = 0;
  int it = 0;
  for (int base = 0; base < NPTS && count < NSAMP; base += 256, ++it) {
    const int m = base + wave * 64 + lane;
    const float4v pv = xq[m];
    const float px = pv[0], py = pv[1], pz = pv[2];
    const float dot = fmaf(qz, pz, fmaf(qy, py, qx * px));
    const float dist = fmaf(-2.f, dot, dqf + pv[3]);
    bool hit;
    if (__ballot(__builtin_fabsf(dist - 0.36f) <= 3e-5f)) {
      // rare exact path: fp64, same evaluation as the np reference
      const double dm = (double)px * px + (double)py * py + (double)pz * pz;
      const double dd = (double)qx * px + (double)qy * py + (double)qz * pz;
      hit = !((dq + dm - 2.0 * dd) > 0.36);
    } else {
      hit = !(dist > 0.36f);
    }
    const unsigned long long mask = __ballot(hit);
    const int par = it & 1;
    if (lane == 0) cnt[par][wave] = (unsigned)__popcll(mask);
    __syncthreads();
    int pre = count;
#pragma unroll
    for (int w = 0; w < 3; ++w)
      if (wave > w) pre += (int)cnt[par][w];
    if (hit) {
      const int pos = pre + __popcll(mask & lt);
      if (pos < NSAMP) list[pos] = m;
    }
    count += (int)(cnt[par][0] + cnt[par][1] + cnt[par][2] + cnt[par][3]);
    // no second barrier: next iteration writes cnt[1-par]; list positions
    // are disjoint across iterations (pos >= count(prev))
  }
  if (count > NSAMP) count = NSAMP;
  __syncthreads();   // make last iteration's list writes visible
  if (t >= count && t < NSAMP) list[t] = list[0];  // self guarantees count>=1
  __syncthreads();

  // ---- Phase 2: coalesced gather. thread t -> rows r*16 + (t>>4),
  //      16-B channel slice (t&15). 4 rounds, one asm burst. ----
  const int rowsel = t >> 4;   // 0..15
  const int csl = t & 15;      // 0..15 (16 B = 8 channels)
  const unsigned long long hb =
      (unsigned long long)(h2 + (size_t)b * NPTS * CH2) + (unsigned)(csl * 16);

  unsigned long long ad[4];
#pragma unroll
  for (int r = 0; r < 4; ++r)
    ad[r] = hb + (unsigned)(list[r * 16 + rowsel] * 256);

  uint4v v0, v1, v2, v3;
  asm volatile(
      "global_load_dwordx4 %0, %4, off\n\t"
      "global_load_dwordx4 %1, %5, off\n\t"
      "global_load_dwordx4 %2, %6, off\n\t"
      "global_load_dwordx4 %3, %7, off\n\t"
      "s_waitcnt vmcnt(0)"
      : "=&v"(v0), "=&v"(v1), "=&v"(v2), "=&v"(v3)
      : "v"(ad[0]), "v"(ad[1]), "v"(ad[2]), "v"(ad[3])
      : "memory");

  partial[t] = pk4max(pk4max(v0, v1), pk4max(v2, v3));
  __syncthreads();

  // ---- Final reduction: 64 threads, one dword (2 channels) each ----
  if (t < 64) {
    const int cs = t >> 2;      // which 16-B slice (0..15)
    const int d  = t & 3;       // dword within slice
    const unsigned* pl = (const unsigned*)&partial[0];
    unsigned m = 0;
#pragma unroll
    for (int rs = 0; rs < 16; ++rs)
      m = pmax(m, pl[(rs * 16 + cs) * 4 + d]);
    const size_t ob = (size_t)b * CH2 * NPTS;
    out[ob + (size_t)(2 * t) * NPTS + s]     = h2lo(m);
    out[ob + (size_t)(2 * t + 1) * NPTS + s] = h2hi(m);
  }
}

// ---------------------------------------------------------------------------
extern "C" void kernel_launch(void* const* d_in, const int* in_sizes, int n_in,
                              void* d_out, int out_size, void* d_ws, size_t ws_size,
                              hipStream_t stream) {
  const float* x  = (const float*)d_in[0];
  const float* W1 = (const float*)d_in[1];
  const float* b1 = (const float*)d_in[2];
  const float* W2 = (const float*)d_in[3];
  const float* b2 = (const float*)d_in[4];
  float* out = (float*)d_out;

  __half*  h2   = (__half*)d_ws;                                     // 4 MB
  float4v* xyzq = (float4v*)((char*)d_ws + (size_t)4 * 1024 * 1024); // 256 KB

  mlp_kernel<<<(BATCH * NPTS) / 32, 256, 0, stream>>>(
      x, W1, b1, W2, b2, h2, xyzq);
  query_kernel<<<BATCH * NPTS, 256, 0, stream>>>(xyzq, h2, out);
}